// Round 1
// baseline (170.629 us; speedup 1.0000x reference)
//
#include <hip/hip_runtime.h>

#define BS 32
#define NA 512
#define ID 128
#define NH 8
#define HD 64
#define NHD 512   // NH*HD
#define NEG 0.2f
#define NC 32
#define CH 16

// K0: fold att_a into W:  wa[k*16+o], o<8 -> src head o, o>=8 -> dst head o-8
__global__ void k0_wa(const float* __restrict__ W, const float* __restrict__ att,
                      float* __restrict__ wa) {
  int idx = blockIdx.x * blockDim.x + threadIdx.x;
  if (idx >= ID * 16) return;
  int k = idx >> 4, o = idx & 15;
  int head = o & 7;
  const float* arow = att + head * 128 + ((o & 8) ? 64 : 0);
  const float* wrow = W + (size_t)k * NHD + head * HD;
  float acc = 0.f;
  #pragma unroll
  for (int d = 0; d < HD; ++d) acc += wrow[d] * arow[d];
  wa[idx] = acc;
}

// K1: h_prime = h @ W  (fp32, 32-row x 512-col block tile, 8x8 per thread)
// + epilogue: s[b,h,n] = h.wa_src, t[b,h,n] = h.wa_dst
__global__ __launch_bounds__(256) void k1_gemm(
    const float* __restrict__ h, const float* __restrict__ W,
    const float* __restrict__ wa, float* __restrict__ hp,
    float* __restrict__ s_out, float* __restrict__ t_out) {
  __shared__ float hs[ID * 36];  // hs[k*36 + r], pad 36 keeps 16B align (144B rows)
  int blk = blockIdx.x;
  int b = blk >> 4;               // 16 blocks per batch
  int n0 = (blk & 15) * 32;
  int t = threadIdx.x;
  const float* hbase = h + ((size_t)b * NA + n0) * ID;
  {
    int r = t >> 3;               // 0..31
    int k0 = (t & 7) * 16;
    const float* src = hbase + r * ID + k0;
    #pragma unroll
    for (int i = 0; i < 16; i += 4) {
      float4 v = *(const float4*)(src + i);
      hs[(k0 + i + 0) * 36 + r] = v.x;
      hs[(k0 + i + 1) * 36 + r] = v.y;
      hs[(k0 + i + 2) * 36 + r] = v.z;
      hs[(k0 + i + 3) * 36 + r] = v.w;
    }
  }
  __syncthreads();
  int lane = t & 63;
  int r0 = (t >> 6) * 8;          // wave-uniform -> LDS broadcast reads
  int c0 = lane * 8;              // wave covers cols 0..511 -> coalesced W reads
  float acc[8][8];
  #pragma unroll
  for (int i = 0; i < 8; ++i)
    #pragma unroll
    for (int j = 0; j < 8; ++j) acc[i][j] = 0.f;
  const float* wptr = W + c0;
  #pragma unroll 4
  for (int k = 0; k < ID; ++k) {
    float4 b0 = *(const float4*)(wptr + (size_t)k * NHD);
    float4 b1 = *(const float4*)(wptr + (size_t)k * NHD + 4);
    float4 a0 = *(const float4*)(&hs[k * 36 + r0]);
    float4 a1 = *(const float4*)(&hs[k * 36 + r0 + 4]);
    float av[8] = {a0.x, a0.y, a0.z, a0.w, a1.x, a1.y, a1.z, a1.w};
    float bv[8] = {b0.x, b0.y, b0.z, b0.w, b1.x, b1.y, b1.z, b1.w};
    #pragma unroll
    for (int i = 0; i < 8; ++i)
      #pragma unroll
      for (int j = 0; j < 8; ++j) acc[i][j] += av[i] * bv[j];
  }
  int head = c0 >> 6;
  int d0 = c0 & 63;
  #pragma unroll
  for (int i = 0; i < 8; ++i) {
    size_t off = ((((size_t)b * NH + head) * NA) + (n0 + r0 + i)) * HD + d0;
    float4 o0 = {acc[i][0], acc[i][1], acc[i][2], acc[i][3]};
    float4 o1 = {acc[i][4], acc[i][5], acc[i][6], acc[i][7]};
    *(float4*)(hp + off) = o0;
    *(float4*)(hp + off + 4) = o1;
  }
  // s/t epilogue: 32 rows x 16 outputs, 2 per thread, from staged hs
  #pragma unroll
  for (int u = 0; u < 2; ++u) {
    int outi = t + u * 256;
    int r = outi >> 4;
    int o = outi & 15;
    float a2 = 0.f;
    for (int k = 0; k < ID; ++k) a2 += hs[k * 36 + r] * wa[k * 16 + o];
    int hh = o & 7;
    size_t off = (((size_t)b * NH + hh) * NA) + (n0 + r);
    if (o < 8) s_out[off] = a2; else t_out[off] = a2;
  }
}

// K2: per-(b,h): sort t, build suffix(e^t v)/prefix(e^.2t v) chunk tables,
// then each thread finishes one row: binary-search cut + one 16-chunk + tables.
__global__ __launch_bounds__(512) void k2_attn(
    const float* __restrict__ hp, const float* __restrict__ s_g,
    const float* __restrict__ t_g, float* __restrict__ out) {
  __shared__ float tv[NA]; __shared__ int tpm[NA];
  __shared__ float sv[NA]; __shared__ int spm[NA];
  __shared__ float wp[NA]; __shared__ float wn[NA];
  __shared__ float rawP[NC * 64]; __shared__ float rawN[NC * 64];
  __shared__ float sufP[(NC + 1) * 64]; __shared__ float preN[(NC + 1) * 64];
  __shared__ float zps[NA + 1]; __shared__ float znp[NA + 1];
  __shared__ float szP[NC]; __shared__ float szN[NC];
  __shared__ float sufZ[NC + 1]; __shared__ float preZ[NC + 1];

  int bh = blockIdx.x;
  int t = threadIdx.x;
  const float* vbase = hp + (size_t)bh * NA * HD;

  tv[t] = t_g[(size_t)bh * NA + t]; tpm[t] = t;
  sv[t] = s_g[(size_t)bh * NA + t]; spm[t] = t;
  __syncthreads();

  // bitonic sort ascending: (tv,tpm) and (sv,spm) in the same passes
  for (int size = 2; size <= NA; size <<= 1) {
    for (int stride = size >> 1; stride > 0; stride >>= 1) {
      int i = t, j = i ^ stride;
      if (j > i) {
        bool up = ((i & size) == 0);
        float a = tv[i], b = tv[j];
        if (up ? (a > b) : (a < b)) {
          tv[i] = b; tv[j] = a;
          int x = tpm[i]; tpm[i] = tpm[j]; tpm[j] = x;
        }
        float c = sv[i], d = sv[j];
        if (up ? (c > d) : (c < d)) {
          sv[i] = d; sv[j] = c;
          int x = spm[i]; spm[i] = spm[j]; spm[j] = x;
        }
      }
      __syncthreads();
    }
  }

  float cmax = fmaxf(tv[NA - 1], 0.f);   // uniform scale e^{-c}
  float amax = fmaxf(sv[NA - 1], 0.f);   // uniform scale e^{-a}
  wp[t] = __expf(tv[t] - cmax);          // pos-branch key weight
  wn[t] = __expf(NEG * tv[t] - cmax);    // neg-branch key weight
  __syncthreads();

  // chunk vector sums over sorted order (coalesced V reads: lane = dim)
  {
    int d = t & 63, w8 = t >> 6;
    for (int cc = w8; cc < NC; cc += 8) {
      float aP = 0.f, aN = 0.f;
      for (int j = cc * CH; j < cc * CH + CH; ++j) {
        float v = vbase[(size_t)tpm[j] * HD + d];
        aP += wp[j] * v;
        aN += wn[j] * v;
      }
      rawP[cc * 64 + d] = aP;
      rawN[cc * 64 + d] = aN;
    }
  }
  __syncthreads();

  // chunk-level scans (vector) + per-chunk scalar sums
  if (t < 64) {
    int d = t; float run = 0.f;
    sufP[NC * 64 + d] = 0.f;
    for (int cc = NC - 1; cc >= 0; --cc) { run += rawP[cc * 64 + d]; sufP[cc * 64 + d] = run; }
  } else if (t < 128) {
    int d = t - 64; float run = 0.f;
    for (int cc = 0; cc <= NC; ++cc) { preN[cc * 64 + d] = run; if (cc < NC) run += rawN[cc * 64 + d]; }
  } else if (t < 160) {
    int c = t - 128; float a = 0.f;
    for (int j = c * CH; j < c * CH + CH; ++j) a += wp[j];
    szP[c] = a;
  } else if (t < 192) {
    int c = t - 160; float a = 0.f;
    for (int j = c * CH; j < c * CH + CH; ++j) a += wn[j];
    szN[c] = a;
  }
  __syncthreads();

  if (t == 0) {
    float run = 0.f; sufZ[NC] = 0.f;
    for (int cc = NC - 1; cc >= 0; --cc) { run += szP[cc]; sufZ[cc] = run; }
  } else if (t == 1) {
    float run = 0.f;
    for (int cc = 0; cc <= NC; ++cc) { preZ[cc] = run; if (cc < NC) run += szN[cc]; }
  }
  __syncthreads();

  // full-resolution scalar tables: zps[j] = sum_{k>=j} wp, znp[j] = sum_{k<j} wn
  {
    int ch = t >> 4;
    float a = 0.f;
    for (int k = t; k < ch * CH + CH; ++k) a += wp[k];
    zps[t] = a + sufZ[ch + 1];
    float b2 = 0.f;
    for (int k = ch * CH; k < t; ++k) b2 += wn[k];
    znp[t] = preZ[ch] + b2;
    if (t == 0) { zps[NA] = 0.f; znp[NA] = preZ[NC]; }
  }
  __syncthreads();

  // pass B: one thread per row (rows sorted by s -> adjacent lanes share chunk)
  {
    float sval = sv[t];
    int row = spm[t];
    float A = __expf(sval - amax);
    float B = __expf(NEG * sval - amax);
    float key = -sval;
    int lo = 0, hi = NA;
    while (lo < hi) { int mid = (lo + hi) >> 1; if (tv[mid] < key) lo = mid + 1; else hi = mid; }
    int js = lo;                       // first sorted idx with t >= -s (pos set)
    int cs = js >> 4; if (cs > NC - 1) cs = NC - 1;
    float den = A * zps[js] + B * znp[js];
    float num[64];
    {
      const float* sp_ = &sufP[(cs + 1) * 64];
      const float* pn_ = &preN[cs * 64];
      #pragma unroll
      for (int d = 0; d < 64; ++d) num[d] = A * sp_[d] + B * pn_[d];
    }
    for (int j = cs * CH; j < cs * CH + CH; ++j) {
      float coef = (j >= js) ? A * wp[j] : B * wn[j];
      const float* vrow = vbase + (size_t)tpm[j] * HD;
      #pragma unroll
      for (int d = 0; d < 64; d += 4) {
        float4 vv = *(const float4*)(vrow + d);
        num[d + 0] += coef * vv.x;
        num[d + 1] += coef * vv.y;
        num[d + 2] += coef * vv.z;
        num[d + 3] += coef * vv.w;
      }
    }
    float inv = 1.f / den;
    float* ob = out + ((size_t)bh * NA + row) * HD;
    #pragma unroll
    for (int d = 0; d < 64; d += 4) {
      float4 ov;
      float x0 = num[d + 0] * inv; ov.x = x0 > 0.f ? x0 : __expf(x0) - 1.f;
      float x1 = num[d + 1] * inv; ov.y = x1 > 0.f ? x1 : __expf(x1) - 1.f;
      float x2 = num[d + 2] * inv; ov.z = x2 > 0.f ? x2 : __expf(x2) - 1.f;
      float x3 = num[d + 3] * inv; ov.w = x3 > 0.f ? x3 : __expf(x3) - 1.f;
      *(float4*)(ob + d) = ov;
    }
  }
}

extern "C" void kernel_launch(void* const* d_in, const int* in_sizes, int n_in,
                              void* d_out, int out_size, void* d_ws, size_t ws_size,
                              hipStream_t stream) {
  const float* h  = (const float*)d_in[0];
  const float* W  = (const float*)d_in[1];
  const float* att = (const float*)d_in[2];
  float* out = (float*)d_out;
  // workspace: hp (33.5MB) | s (512KB) | t (512KB) | wa (8KB)
  float* hp    = (float*)d_ws;
  float* s_arr = hp + (size_t)BS * NH * NA * HD;
  float* t_arr = s_arr + (size_t)BS * NH * NA;
  float* wa    = t_arr + (size_t)BS * NH * NA;

  k0_wa  <<<dim3(8),   dim3(256), 0, stream>>>(W, att, wa);
  k1_gemm<<<dim3(512), dim3(256), 0, stream>>>(h, W, wa, hp, s_arr, t_arr);
  k2_attn<<<dim3(256), dim3(512), 0, stream>>>(hp, s_arr, t_arr, out);
}